// Round 3
// baseline (203.159 us; speedup 1.0000x reference)
//
#include <hip/hip_runtime.h>

#define N_NODES 50000
#define N_EDGES 400000
#define DIM 160
#define NB 64
#define CUTOFF 5.0f
#define LN_EPS 1e-5f
#define PI_F 3.14159265358979323846f

// Padded CSR: stride-64 slot list per destination node.
// max in-degree ~ Poisson(8) over 50k nodes ~ 28; P(>=64) ~ 1e-40.
#define SLOT_STRIDE 64

// Workspace (ints):
//   [0..15]  ew accumulator (float) + pad
//   deg[N]
//   pkt[64]  (float4 per RBF bucket: {center, 1/width, proj_w, 0})
//   pos4[N]  (float4 per node)
//   esrc[N*64]
#define WS_DEG   16
#define WS_PKT   (WS_DEG + N_NODES)          // byte 200064, 16B aligned
#define WS_POS4  (WS_PKT + 4 * NB)           // byte 201088, 16B aligned
#define WS_ESRC  (WS_POS4 + 4 * N_NODES)     // byte 1001088, 16B aligned

// ---------------------------------------------------------------------------
// K0: prep. Zeroes ew + deg, packs pos into float4 rows, and packs the RBF
// table into ONE float4 per bucket ({c, 1/w, p, 0}) so K1's inner loop is a
// single L1-resident broadcast dwordx4 per bucket instead of 3 ds_read_b32
// (the round-1 counters showed hist was LDS-issue-pipe bound: 192 LDS reads
// per edge-thread, VALUBusy only 12.6%).
// ---------------------------------------------------------------------------
__global__ __launch_bounds__(256) void prep(
    const float* __restrict__ pos, const float* __restrict__ centers,
    const float* __restrict__ widths, const float* __restrict__ proj_w,
    int* __restrict__ deg, float4* __restrict__ pkt,
    float4* __restrict__ pos4, float* __restrict__ ew_accum)
{
    const int i = blockIdx.x * blockDim.x + threadIdx.x;
    if (i < 16) ((int*)ew_accum)[i] = 0;
    if (i < NB)
        pkt[i] = make_float4(centers[i], 1.0f / widths[i], proj_w[i], 0.0f);
    if (i < N_NODES) {
        deg[i] = 0;
        pos4[i] = make_float4(pos[3 * i], pos[3 * i + 1], pos[3 * i + 2], 0.0f);
    }
}

// ---------------------------------------------------------------------------
// K1: thread-per-edge. Fused: edge_w sigmoid sum + degree count + padded-CSR
// slot fill (rides the same atomicAdd that produced the degree).
// RBF table via broadcast float4 loads (L1-hot, no LDS pipe).
// ---------------------------------------------------------------------------
__global__ __launch_bounds__(256) void hist_ew_fill(
    const int* __restrict__ ei, const float4* __restrict__ pos4,
    const float4* __restrict__ pkt, const float* __restrict__ proj_b,
    int* __restrict__ deg, int* __restrict__ esrc, float* __restrict__ ew_accum)
{
    const float bias = proj_b[0];
    const int e = blockIdx.x * blockDim.x + threadIdx.x;
    float sig = 0.0f;
    if (e < N_EDGES) {
        const int s = ei[e];
        const int d = ei[N_EDGES + e];

        // degree count + slot assignment in one atomic (issued first; the
        // dependent scattered store overlaps the pos gather + RBF loop)
        const int slot = atomicAdd(&deg[d], 1);

        const float4 ps = pos4[s];
        const float4 pd = pos4[d];

        if (slot < SLOT_STRIDE)
            esrc[((long)d << 6) + slot] = s;

        const float dx = ps.x - pd.x;
        const float dy = ps.y - pd.y;
        const float dz = ps.z - pd.z;
        const float dist = sqrtf(dx * dx + dy * dy + dz * dz);

        float z = 0.0f;
        #pragma unroll 8
        for (int b = 0; b < NB; ++b) {
            const float4 t4 = pkt[b];               // broadcast, L1-hot
            const float t = (dist - t4.x) * t4.y;
            z = fmaf(__expf(-0.5f * t * t), t4.z, z);
        }
        const float cut = (dist <= CUTOFF)
                        ? 0.5f * (__cosf(PI_F * dist * (1.0f / CUTOFF)) + 1.0f)
                        : 0.0f;
        sig = 1.0f / (1.0f + __expf(-(z * cut + bias)));
    }

    #pragma unroll
    for (int off = 32; off > 0; off >>= 1) sig += __shfl_xor(sig, off);
    __shared__ float red[4];
    if ((threadIdx.x & 63) == 0) red[threadIdx.x >> 6] = sig;
    __syncthreads();
    if (threadIdx.x == 0)
        atomicAdd(ew_accum, red[0] + red[1] + red[2] + red[3]);
}

// ---------------------------------------------------------------------------
// K2: wave-per-node gather from padded slot lists. deg <= ~28 so the whole
// list fits one 64-lane batch; 8-wide unroll keeps 8 dwordx4 loads in flight
// per accumulate group (latency-bound regime).
// ---------------------------------------------------------------------------
__global__ __launch_bounds__(256) void gather_pass(
    const float* __restrict__ x, const int* __restrict__ deg,
    const int* __restrict__ esrc, float* __restrict__ agg)
{
    const int lane = threadIdx.x & 63;
    const int n    = (blockIdx.x * blockDim.x + threadIdx.x) >> 6;
    if (n >= N_NODES) return;

    const int cnt = min(deg[n], SLOT_STRIDE);
    const int sv  = (lane < cnt) ? esrc[((long)n << 6) + lane] : 0;

    float4 acc = make_float4(0.f, 0.f, 0.f, 0.f);
    int j = 0;
    for (; j + 8 <= cnt; j += 8) {
        const int s0 = __shfl(sv, j);
        const int s1 = __shfl(sv, j + 1);
        const int s2 = __shfl(sv, j + 2);
        const int s3 = __shfl(sv, j + 3);
        const int s4 = __shfl(sv, j + 4);
        const int s5 = __shfl(sv, j + 5);
        const int s6 = __shfl(sv, j + 6);
        const int s7 = __shfl(sv, j + 7);
        if (lane < 40) {
            const float4 v0 = ((const float4*)(x + (long)s0 * DIM))[lane];
            const float4 v1 = ((const float4*)(x + (long)s1 * DIM))[lane];
            const float4 v2 = ((const float4*)(x + (long)s2 * DIM))[lane];
            const float4 v3 = ((const float4*)(x + (long)s3 * DIM))[lane];
            const float4 v4 = ((const float4*)(x + (long)s4 * DIM))[lane];
            const float4 v5 = ((const float4*)(x + (long)s5 * DIM))[lane];
            const float4 v6 = ((const float4*)(x + (long)s6 * DIM))[lane];
            const float4 v7 = ((const float4*)(x + (long)s7 * DIM))[lane];
            acc.x += ((v0.x + v1.x) + (v2.x + v3.x)) + ((v4.x + v5.x) + (v6.x + v7.x));
            acc.y += ((v0.y + v1.y) + (v2.y + v3.y)) + ((v4.y + v5.y) + (v6.y + v7.y));
            acc.z += ((v0.z + v1.z) + (v2.z + v3.z)) + ((v4.z + v5.z) + (v6.z + v7.z));
            acc.w += ((v0.w + v1.w) + (v2.w + v3.w)) + ((v4.w + v5.w) + (v6.w + v7.w));
        }
    }
    for (; j + 4 <= cnt; j += 4) {
        const int s0 = __shfl(sv, j);
        const int s1 = __shfl(sv, j + 1);
        const int s2 = __shfl(sv, j + 2);
        const int s3 = __shfl(sv, j + 3);
        if (lane < 40) {
            const float4 v0 = ((const float4*)(x + (long)s0 * DIM))[lane];
            const float4 v1 = ((const float4*)(x + (long)s1 * DIM))[lane];
            const float4 v2 = ((const float4*)(x + (long)s2 * DIM))[lane];
            const float4 v3 = ((const float4*)(x + (long)s3 * DIM))[lane];
            acc.x += (v0.x + v1.x) + (v2.x + v3.x);
            acc.y += (v0.y + v1.y) + (v2.y + v3.y);
            acc.z += (v0.z + v1.z) + (v2.z + v3.z);
            acc.w += (v0.w + v1.w) + (v2.w + v3.w);
        }
    }
    for (; j < cnt; ++j) {
        const int s0 = __shfl(sv, j);
        if (lane < 40) {
            const float4 v0 = ((const float4*)(x + (long)s0 * DIM))[lane];
            acc.x += v0.x; acc.y += v0.y; acc.z += v0.z; acc.w += v0.w;
        }
    }
    if (lane < 40)
        ((float4*)(agg + (long)n * DIM))[lane] = acc;
}

// ---------------------------------------------------------------------------
// K3: LDS-tiled node transform. Block owns 64 nodes; rows + W0 + W1 staged in
// LDS; scalar channel (W0 + LN + SiLU) and vector channel (W1, rotation
// cancels since R^T R = I) computed from LDS.
//   Row pad +4 (ROWP=164): per-node b32/b128 reads land 2-way per bank (free).
// In-place on agg. LDS = 41984 + 16384 + 4096 = 62464 B -> 2 blocks/CU.
// ---------------------------------------------------------------------------
#define ROWP 164
#define TNODES 64

__global__ __launch_bounds__(256) void node_tiled(
    float* __restrict__ agg,
    const float* __restrict__ W0, const float* __restrict__ W1,
    const float* __restrict__ ln_gamma, const float* __restrict__ ln_beta,
    const float* __restrict__ ew_accum)
{
    __shared__ float sA[TNODES * ROWP];   // 64 x 164 floats
    __shared__ float sW0[64 * 64];
    __shared__ float sW1[32 * 32];

    const int t = threadIdx.x;
    const int node0 = blockIdx.x * TNODES;

    // ---- stage weights (coalesced, L2-hot) ----
    {
        const float4* w04 = (const float4*)W0;   // 1024 float4
        float4* s04 = (float4*)sW0;
        #pragma unroll
        for (int i = 0; i < 4; ++i) s04[t + 256 * i] = w04[t + 256 * i];
        ((float4*)sW1)[t] = ((const float4*)W1)[t];   // 256 float4
    }
    // ---- stage 64 rows (coalesced float4, guarded) ----
    {
        #pragma unroll
        for (int i = 0; i < 10; ++i) {
            const int idx = t + 256 * i;         // 0..2559
            const int r   = idx / 40;
            const int c4  = idx - r * 40;
            const int n   = node0 + r;
            float4 v = make_float4(0.f, 0.f, 0.f, 0.f);
            if (n < N_NODES) v = ((const float4*)(agg + (long)n * DIM))[c4];
            *(float4*)(&sA[r * ROWP + 4 * c4]) = v;
        }
    }
    __syncthreads();

    const float ew   = ew_accum[0] * (1.0f / 400000.0f);
    const float s_m0 = ew * 0.125f;                 // / sqrt(64)
    const float s_m1 = ew * 0.17677669529663687f;   // / sqrt(32)

    const int nl   = t >> 2;          // 0..63 node within tile
    const int sub  = t & 3;           // chunk / c8
    const int node = node0 + nl;
    const bool valid = node < N_NODES;
    float* grow = agg + (long)(valid ? node : 0) * DIM;
    const float* aRow = sA + nl * ROWP;

    // ---------------- scalar channel ----------------
    float acc[16];
    #pragma unroll
    for (int j = 0; j < 16; ++j) acc[j] = 0.0f;

    #pragma unroll 8
    for (int k = 0; k < 64; ++k) {
        const float a = aRow[k];                        // ds b32, 2-way/bank
        const float4* w4 = (const float4*)(sW0 + k * 64 + sub * 16);
        #pragma unroll
        for (int p = 0; p < 4; ++p) {
            const float4 wv = w4[p];
            acc[4 * p]     = fmaf(a, wv.x, acc[4 * p]);
            acc[4 * p + 1] = fmaf(a, wv.y, acc[4 * p + 1]);
            acc[4 * p + 2] = fmaf(a, wv.z, acc[4 * p + 2]);
            acc[4 * p + 3] = fmaf(a, wv.w, acc[4 * p + 3]);
        }
    }

    float sum = 0.0f, sumsq = 0.0f;
    #pragma unroll
    for (int j = 0; j < 16; ++j) {
        acc[j] *= s_m0;
        sum += acc[j];
        sumsq = fmaf(acc[j], acc[j], sumsq);
    }
    sum += __shfl_xor(sum, 1);  sumsq += __shfl_xor(sumsq, 1);
    sum += __shfl_xor(sum, 2);  sumsq += __shfl_xor(sumsq, 2);
    const float mu   = sum * (1.0f / 64.0f);
    const float var  = sumsq * (1.0f / 64.0f) - mu * mu;
    const float rstd = rsqrtf(var + LN_EPS);

    if (valid) {
        const float4* g4 = (const float4*)(ln_gamma + sub * 16);
        const float4* b4 = (const float4*)(ln_beta  + sub * 16);
        float4* ro4 = (float4*)(grow + sub * 16);
        #pragma unroll
        for (int p = 0; p < 4; ++p) {
            const float4 g = g4[p];
            const float4 b = b4[p];
            const float t0 = (acc[4 * p]     - mu) * rstd * g.x + b.x;
            const float t1 = (acc[4 * p + 1] - mu) * rstd * g.y + b.y;
            const float t2 = (acc[4 * p + 2] - mu) * rstd * g.z + b.z;
            const float t3 = (acc[4 * p + 3] - mu) * rstd * g.w + b.w;
            float4 o;
            o.x = t0 / (1.0f + __expf(-t0));
            o.y = t1 / (1.0f + __expf(-t1));
            o.z = t2 / (1.0f + __expf(-t2));
            o.w = t3 / (1.0f + __expf(-t3));
            ro4[p] = o;
        }
    }

    // ---------------- vector channel ----------------
    float o[24];
    #pragma unroll
    for (int m = 0; m < 24; ++m) o[m] = 0.0f;

    const float* bRow = aRow + 64;
    #pragma unroll 2
    for (int tt = 0; tt < 8; ++tt) {            // cp = 4tt + r
        const float4 v0 = *(const float4*)(bRow + 12 * tt);
        const float4 v1 = *(const float4*)(bRow + 12 * tt + 4);
        const float4 v2 = *(const float4*)(bRow + 12 * tt + 8);
        const float a[12] = { v0.x, v0.y, v0.z, v0.w,
                              v1.x, v1.y, v1.z, v1.w,
                              v2.x, v2.y, v2.z, v2.w };
        #pragma unroll
        for (int r = 0; r < 4; ++r) {
            const int cp = 4 * tt + r;
            const float a0 = a[3 * r];
            const float a1 = a[3 * r + 1];
            const float a2 = a[3 * r + 2];
            const float4* w4 = (const float4*)(sW1 + cp * 32 + sub * 8);
            const float4 wA = w4[0];
            const float4 wB = w4[1];
            const float wc[8] = { wA.x, wA.y, wA.z, wA.w, wB.x, wB.y, wB.z, wB.w };
            #pragma unroll
            for (int cc = 0; cc < 8; ++cc) {
                o[3 * cc]     = fmaf(wc[cc], a0, o[3 * cc]);
                o[3 * cc + 1] = fmaf(wc[cc], a1, o[3 * cc + 1]);
                o[3 * cc + 2] = fmaf(wc[cc], a2, o[3 * cc + 2]);
            }
        }
    }

    if (valid) {
        float4* ro4 = (float4*)(grow + 64 + 24 * sub);
        #pragma unroll
        for (int q = 0; q < 6; ++q) {
            float4 ov;
            ov.x = o[4 * q]     * s_m1;
            ov.y = o[4 * q + 1] * s_m1;
            ov.z = o[4 * q + 2] * s_m1;
            ov.w = o[4 * q + 3] * s_m1;
            ro4[q] = ov;
        }
    }
}

extern "C" void kernel_launch(void* const* d_in, const int* in_sizes, int n_in,
                              void* d_out, int out_size, void* d_ws, size_t ws_size,
                              hipStream_t stream) {
    const float* x       = (const float*)d_in[0];
    const float* pos     = (const float*)d_in[1];
    const int*   ei      = (const int*)d_in[2];
    const float* W0      = (const float*)d_in[4];
    const float* W1      = (const float*)d_in[5];
    const float* centers = (const float*)d_in[6];
    const float* widths  = (const float*)d_in[7];
    const float* proj_w  = (const float*)d_in[8];
    const float* proj_b  = (const float*)d_in[9];
    const float* gamma   = (const float*)d_in[10];
    const float* beta    = (const float*)d_in[11];

    float* out  = (float*)d_out;
    int*   wsi  = (int*)d_ws;
    float* ew   = (float*)d_ws;
    int*   deg  = wsi + WS_DEG;
    float4* pkt  = (float4*)(wsi + WS_PKT);
    float4* pos4 = (float4*)(wsi + WS_POS4);
    int*   esrc = wsi + WS_ESRC;

    const int pb = (N_NODES + 255) / 256;
    prep<<<pb, 256, 0, stream>>>(pos, centers, widths, proj_w, deg, pkt, pos4, ew);

    const int eb = (N_EDGES + 255) / 256;
    hist_ew_fill<<<eb, 256, 0, stream>>>(ei, pos4, pkt, proj_b, deg, esrc, ew);

    const int nb = (N_NODES * 64 + 255) / 256;
    gather_pass<<<nb, 256, 0, stream>>>(x, deg, esrc, out);

    const int tiles = (N_NODES + TNODES - 1) / TNODES;   // 782
    node_tiled<<<tiles, 256, 0, stream>>>(out, W0, W1, gamma, beta, ew);
}

// Round 5
// 193.243 us; speedup vs baseline: 1.0513x; 1.0513x over previous
//
#include <hip/hip_runtime.h>

#define N_NODES 50000
#define N_EDGES 400000
#define DIM 160
#define NB 64
#define CUTOFF 5.0f
#define LN_EPS 1e-5f
#define PI_F 3.14159265358979323846f

// Padded CSR: stride-64 slot list per destination node.
// max in-degree ~ Poisson(8) over 50k nodes ~ 28; P(>=64) ~ 1e-40.
#define SLOT_STRIDE 64

// deg padded to one counter per 16B (4/64B-line): 4x less line-level
// serialization at the coherence point vs unpadded, while keeping the
// TOTAL workspace <= 16 MiB (round-4's 64B padding overflowed the 16 MiB
// workspace: 16.02 MiB -> container fault).
#define DEG_STRIDE 4

// Workspace (ints), total 3,600,272 ints = 13.73 MiB (< 16 MiB cap):
//   [0..15]     ew accumulator (float) + pad
//   degp[N*4]   16B-padded degree counters (0.8 MB)
//   pkt[64]     (float4 per RBF bucket: {center, 1/width, proj_w, 0})
//   pos4[N]     (float4 per node)
//   esrc[N*64]  padded CSR slots (12.8 MB)
#define WS_DEG   16
#define WS_PKT   (WS_DEG + N_NODES * DEG_STRIDE)   // 200016 -> 16B aligned
#define WS_POS4  (WS_PKT + 4 * NB)                 // 200272 -> 16B aligned
#define WS_ESRC  (WS_POS4 + 4 * N_NODES)           // 400272 -> 16B aligned

// ---------------------------------------------------------------------------
// K0: prep. Zeroes ew + padded deg (one int4 per node), packs pos into
// float4 rows, packs RBF table into one float4 per bucket.
// ---------------------------------------------------------------------------
__global__ __launch_bounds__(256) void prep(
    const float* __restrict__ pos, const float* __restrict__ centers,
    const float* __restrict__ widths, const float* __restrict__ proj_w,
    int* __restrict__ degp, float4* __restrict__ pkt,
    float4* __restrict__ pos4, float* __restrict__ ew_accum)
{
    const int i = blockIdx.x * blockDim.x + threadIdx.x;
    if (i < 16) ((int*)ew_accum)[i] = 0;
    if (i < NB)
        pkt[i] = make_float4(centers[i], 1.0f / widths[i], proj_w[i], 0.0f);
    if (i < N_NODES) {
        ((int4*)(degp))[i] = make_int4(0, 0, 0, 0);   // one 16B line per node
        pos4[i] = make_float4(pos[3 * i], pos[3 * i + 1], pos[3 * i + 2], 0.0f);
    }
}

// ---------------------------------------------------------------------------
// K1: 4 edges per thread. Fused: edge_w sigmoid sum + degree count + padded-
// CSR slot fill. The 4 atomic-with-return chains and 8 pos4 loads are all
// independent (memory-level parallelism 4x over thread-per-edge); the 4 RBF
// evaluations share each pkt[b] broadcast load.
// ---------------------------------------------------------------------------
#define EPT 4

__global__ __launch_bounds__(256) void hist_ew_fill(
    const int* __restrict__ ei, const float4* __restrict__ pos4,
    const float4* __restrict__ pkt, const float* __restrict__ proj_b,
    int* __restrict__ degp, int* __restrict__ esrc, float* __restrict__ ew_accum)
{
    const float bias = proj_b[0];
    const int base = blockIdx.x * (256 * EPT) + threadIdx.x;

    int  s[EPT], d[EPT], slot[EPT];
    bool v[EPT];
    #pragma unroll
    for (int k = 0; k < EPT; ++k) {
        const int e = base + 256 * k;
        v[k] = (e < N_EDGES);
        s[k] = v[k] ? ei[e] : 0;
        d[k] = v[k] ? ei[N_EDGES + e] : 0;
    }

    // 4 independent atomic-with-return chains in flight
    #pragma unroll
    for (int k = 0; k < EPT; ++k)
        slot[k] = v[k] ? atomicAdd(&degp[(long)d[k] * DEG_STRIDE], 1) : 0;

    // 8 independent endpoint loads (safe: s/d are 0 when invalid)
    float4 ps[EPT], pd[EPT];
    #pragma unroll
    for (int k = 0; k < EPT; ++k) { ps[k] = pos4[s[k]]; pd[k] = pos4[d[k]]; }

    #pragma unroll
    for (int k = 0; k < EPT; ++k)
        if (v[k] && slot[k] < SLOT_STRIDE)
            esrc[((long)d[k] << 6) + slot[k]] = s[k];

    float dist[EPT];
    #pragma unroll
    for (int k = 0; k < EPT; ++k) {
        const float dx = ps[k].x - pd[k].x;
        const float dy = ps[k].y - pd[k].y;
        const float dz = ps[k].z - pd[k].z;
        dist[k] = sqrtf(dx * dx + dy * dy + dz * dz);
    }

    float z[EPT] = {0.f, 0.f, 0.f, 0.f};
    #pragma unroll 4
    for (int b = 0; b < NB; ++b) {
        const float4 t4 = pkt[b];               // broadcast, L1-hot
        #pragma unroll
        for (int k = 0; k < EPT; ++k) {
            const float t = (dist[k] - t4.x) * t4.y;
            z[k] = fmaf(__expf(-0.5f * t * t), t4.z, z[k]);
        }
    }

    float sig = 0.0f;
    #pragma unroll
    for (int k = 0; k < EPT; ++k) {
        if (v[k]) {
            const float cut = (dist[k] <= CUTOFF)
                            ? 0.5f * (__cosf(PI_F * dist[k] * (1.0f / CUTOFF)) + 1.0f)
                            : 0.0f;
            sig += 1.0f / (1.0f + __expf(-(z[k] * cut + bias)));
        }
    }

    #pragma unroll
    for (int off = 32; off > 0; off >>= 1) sig += __shfl_xor(sig, off);
    __shared__ float red[4];
    if ((threadIdx.x & 63) == 0) red[threadIdx.x >> 6] = sig;
    __syncthreads();
    if (threadIdx.x == 0)
        atomicAdd(ew_accum, red[0] + red[1] + red[2] + red[3]);
}

// ---------------------------------------------------------------------------
// K2: wave-per-node gather from padded slot lists. deg <= ~28 so the whole
// list fits one 64-lane batch; 8-wide unroll keeps 8 dwordx4 loads in flight
// per accumulate group (latency-bound regime).
// ---------------------------------------------------------------------------
__global__ __launch_bounds__(256) void gather_pass(
    const float* __restrict__ x, const int* __restrict__ degp,
    const int* __restrict__ esrc, float* __restrict__ agg)
{
    const int lane = threadIdx.x & 63;
    const int n    = (blockIdx.x * blockDim.x + threadIdx.x) >> 6;
    if (n >= N_NODES) return;

    const int cnt = min(degp[(long)n * DEG_STRIDE], SLOT_STRIDE);
    const int sv  = (lane < cnt) ? esrc[((long)n << 6) + lane] : 0;

    float4 acc = make_float4(0.f, 0.f, 0.f, 0.f);
    int j = 0;
    for (; j + 8 <= cnt; j += 8) {
        const int s0 = __shfl(sv, j);
        const int s1 = __shfl(sv, j + 1);
        const int s2 = __shfl(sv, j + 2);
        const int s3 = __shfl(sv, j + 3);
        const int s4 = __shfl(sv, j + 4);
        const int s5 = __shfl(sv, j + 5);
        const int s6 = __shfl(sv, j + 6);
        const int s7 = __shfl(sv, j + 7);
        if (lane < 40) {
            const float4 v0 = ((const float4*)(x + (long)s0 * DIM))[lane];
            const float4 v1 = ((const float4*)(x + (long)s1 * DIM))[lane];
            const float4 v2 = ((const float4*)(x + (long)s2 * DIM))[lane];
            const float4 v3 = ((const float4*)(x + (long)s3 * DIM))[lane];
            const float4 v4 = ((const float4*)(x + (long)s4 * DIM))[lane];
            const float4 v5 = ((const float4*)(x + (long)s5 * DIM))[lane];
            const float4 v6 = ((const float4*)(x + (long)s6 * DIM))[lane];
            const float4 v7 = ((const float4*)(x + (long)s7 * DIM))[lane];
            acc.x += ((v0.x + v1.x) + (v2.x + v3.x)) + ((v4.x + v5.x) + (v6.x + v7.x));
            acc.y += ((v0.y + v1.y) + (v2.y + v3.y)) + ((v4.y + v5.y) + (v6.y + v7.y));
            acc.z += ((v0.z + v1.z) + (v2.z + v3.z)) + ((v4.z + v5.z) + (v6.z + v7.z));
            acc.w += ((v0.w + v1.w) + (v2.w + v3.w)) + ((v4.w + v5.w) + (v6.w + v7.w));
        }
    }
    for (; j + 4 <= cnt; j += 4) {
        const int s0 = __shfl(sv, j);
        const int s1 = __shfl(sv, j + 1);
        const int s2 = __shfl(sv, j + 2);
        const int s3 = __shfl(sv, j + 3);
        if (lane < 40) {
            const float4 v0 = ((const float4*)(x + (long)s0 * DIM))[lane];
            const float4 v1 = ((const float4*)(x + (long)s1 * DIM))[lane];
            const float4 v2 = ((const float4*)(x + (long)s2 * DIM))[lane];
            const float4 v3 = ((const float4*)(x + (long)s3 * DIM))[lane];
            acc.x += (v0.x + v1.x) + (v2.x + v3.x);
            acc.y += (v0.y + v1.y) + (v2.y + v3.y);
            acc.z += (v0.z + v1.z) + (v2.z + v3.z);
            acc.w += (v0.w + v1.w) + (v2.w + v3.w);
        }
    }
    for (; j < cnt; ++j) {
        const int s0 = __shfl(sv, j);
        if (lane < 40) {
            const float4 v0 = ((const float4*)(x + (long)s0 * DIM))[lane];
            acc.x += v0.x; acc.y += v0.y; acc.z += v0.z; acc.w += v0.w;
        }
    }
    if (lane < 40)
        ((float4*)(agg + (long)n * DIM))[lane] = acc;
}

// ---------------------------------------------------------------------------
// K3: LDS-tiled node transform. Block owns 64 nodes; rows + W0 + W1 staged in
// LDS; scalar channel (W0 + LN + SiLU) and vector channel (W1, rotation
// cancels since R^T R = I) computed from LDS.
//   Row pad +4 (ROWP=164): per-node b32/b128 reads land 2-way per bank (free).
// In-place on agg. LDS = 41984 + 16384 + 4096 = 62464 B -> 2 blocks/CU.
// ---------------------------------------------------------------------------
#define ROWP 164
#define TNODES 64

__global__ __launch_bounds__(256) void node_tiled(
    float* __restrict__ agg,
    const float* __restrict__ W0, const float* __restrict__ W1,
    const float* __restrict__ ln_gamma, const float* __restrict__ ln_beta,
    const float* __restrict__ ew_accum)
{
    __shared__ float sA[TNODES * ROWP];   // 64 x 164 floats
    __shared__ float sW0[64 * 64];
    __shared__ float sW1[32 * 32];

    const int t = threadIdx.x;
    const int node0 = blockIdx.x * TNODES;

    // ---- stage weights (coalesced, L2-hot) ----
    {
        const float4* w04 = (const float4*)W0;   // 1024 float4
        float4* s04 = (float4*)sW0;
        #pragma unroll
        for (int i = 0; i < 4; ++i) s04[t + 256 * i] = w04[t + 256 * i];
        ((float4*)sW1)[t] = ((const float4*)W1)[t];   // 256 float4
    }
    // ---- stage 64 rows (coalesced float4, guarded) ----
    {
        #pragma unroll
        for (int i = 0; i < 10; ++i) {
            const int idx = t + 256 * i;         // 0..2559
            const int r   = idx / 40;
            const int c4  = idx - r * 40;
            const int n   = node0 + r;
            float4 v = make_float4(0.f, 0.f, 0.f, 0.f);
            if (n < N_NODES) v = ((const float4*)(agg + (long)n * DIM))[c4];
            *(float4*)(&sA[r * ROWP + 4 * c4]) = v;
        }
    }
    __syncthreads();

    const float ew   = ew_accum[0] * (1.0f / 400000.0f);
    const float s_m0 = ew * 0.125f;                 // / sqrt(64)
    const float s_m1 = ew * 0.17677669529663687f;   // / sqrt(32)

    const int nl   = t >> 2;          // 0..63 node within tile
    const int sub  = t & 3;           // chunk / c8
    const int node = node0 + nl;
    const bool valid = node < N_NODES;
    float* grow = agg + (long)(valid ? node : 0) * DIM;
    const float* aRow = sA + nl * ROWP;

    // ---------------- scalar channel ----------------
    float acc[16];
    #pragma unroll
    for (int j = 0; j < 16; ++j) acc[j] = 0.0f;

    #pragma unroll 8
    for (int k = 0; k < 64; ++k) {
        const float a = aRow[k];                        // ds b32, 2-way/bank
        const float4* w4 = (const float4*)(sW0 + k * 64 + sub * 16);
        #pragma unroll
        for (int p = 0; p < 4; ++p) {
            const float4 wv = w4[p];
            acc[4 * p]     = fmaf(a, wv.x, acc[4 * p]);
            acc[4 * p + 1] = fmaf(a, wv.y, acc[4 * p + 1]);
            acc[4 * p + 2] = fmaf(a, wv.z, acc[4 * p + 2]);
            acc[4 * p + 3] = fmaf(a, wv.w, acc[4 * p + 3]);
        }
    }

    float sum = 0.0f, sumsq = 0.0f;
    #pragma unroll
    for (int j = 0; j < 16; ++j) {
        acc[j] *= s_m0;
        sum += acc[j];
        sumsq = fmaf(acc[j], acc[j], sumsq);
    }
    sum += __shfl_xor(sum, 1);  sumsq += __shfl_xor(sumsq, 1);
    sum += __shfl_xor(sum, 2);  sumsq += __shfl_xor(sumsq, 2);
    const float mu   = sum * (1.0f / 64.0f);
    const float var  = sumsq * (1.0f / 64.0f) - mu * mu;
    const float rstd = rsqrtf(var + LN_EPS);

    if (valid) {
        const float4* g4 = (const float4*)(ln_gamma + sub * 16);
        const float4* b4 = (const float4*)(ln_beta  + sub * 16);
        float4* ro4 = (float4*)(grow + sub * 16);
        #pragma unroll
        for (int p = 0; p < 4; ++p) {
            const float4 g = g4[p];
            const float4 b = b4[p];
            const float t0 = (acc[4 * p]     - mu) * rstd * g.x + b.x;
            const float t1 = (acc[4 * p + 1] - mu) * rstd * g.y + b.y;
            const float t2 = (acc[4 * p + 2] - mu) * rstd * g.z + b.z;
            const float t3 = (acc[4 * p + 3] - mu) * rstd * g.w + b.w;
            float4 o;
            o.x = t0 / (1.0f + __expf(-t0));
            o.y = t1 / (1.0f + __expf(-t1));
            o.z = t2 / (1.0f + __expf(-t2));
            o.w = t3 / (1.0f + __expf(-t3));
            ro4[p] = o;
        }
    }

    // ---------------- vector channel ----------------
    float o[24];
    #pragma unroll
    for (int m = 0; m < 24; ++m) o[m] = 0.0f;

    const float* bRow = aRow + 64;
    #pragma unroll 2
    for (int tt = 0; tt < 8; ++tt) {            // cp = 4tt + r
        const float4 v0 = *(const float4*)(bRow + 12 * tt);
        const float4 v1 = *(const float4*)(bRow + 12 * tt + 4);
        const float4 v2 = *(const float4*)(bRow + 12 * tt + 8);
        const float a[12] = { v0.x, v0.y, v0.z, v0.w,
                              v1.x, v1.y, v1.z, v1.w,
                              v2.x, v2.y, v2.z, v2.w };
        #pragma unroll
        for (int r = 0; r < 4; ++r) {
            const int cp = 4 * tt + r;
            const float a0 = a[3 * r];
            const float a1 = a[3 * r + 1];
            const float a2 = a[3 * r + 2];
            const float4* w4 = (const float4*)(sW1 + cp * 32 + sub * 8);
            const float4 wA = w4[0];
            const float4 wB = w4[1];
            const float wc[8] = { wA.x, wA.y, wA.z, wA.w, wB.x, wB.y, wB.z, wB.w };
            #pragma unroll
            for (int cc = 0; cc < 8; ++cc) {
                o[3 * cc]     = fmaf(wc[cc], a0, o[3 * cc]);
                o[3 * cc + 1] = fmaf(wc[cc], a1, o[3 * cc + 1]);
                o[3 * cc + 2] = fmaf(wc[cc], a2, o[3 * cc + 2]);
            }
        }
    }

    if (valid) {
        float4* ro4 = (float4*)(grow + 64 + 24 * sub);
        #pragma unroll
        for (int q = 0; q < 6; ++q) {
            float4 ov;
            ov.x = o[4 * q]     * s_m1;
            ov.y = o[4 * q + 1] * s_m1;
            ov.z = o[4 * q + 2] * s_m1;
            ov.w = o[4 * q + 3] * s_m1;
            ro4[q] = ov;
        }
    }
}

extern "C" void kernel_launch(void* const* d_in, const int* in_sizes, int n_in,
                              void* d_out, int out_size, void* d_ws, size_t ws_size,
                              hipStream_t stream) {
    const float* x       = (const float*)d_in[0];
    const float* pos     = (const float*)d_in[1];
    const int*   ei      = (const int*)d_in[2];
    const float* W0      = (const float*)d_in[4];
    const float* W1      = (const float*)d_in[5];
    const float* centers = (const float*)d_in[6];
    const float* widths  = (const float*)d_in[7];
    const float* proj_w  = (const float*)d_in[8];
    const float* proj_b  = (const float*)d_in[9];
    const float* gamma   = (const float*)d_in[10];
    const float* beta    = (const float*)d_in[11];

    float* out  = (float*)d_out;
    int*   wsi  = (int*)d_ws;
    float* ew   = (float*)d_ws;
    int*   degp = wsi + WS_DEG;
    float4* pkt  = (float4*)(wsi + WS_PKT);
    float4* pos4 = (float4*)(wsi + WS_POS4);
    int*   esrc = wsi + WS_ESRC;

    const int pb = (N_NODES + 255) / 256;
    prep<<<pb, 256, 0, stream>>>(pos, centers, widths, proj_w, degp, pkt, pos4, ew);

    const int eb = (N_EDGES + 256 * EPT - 1) / (256 * EPT);   // 391
    hist_ew_fill<<<eb, 256, 0, stream>>>(ei, pos4, pkt, proj_b, degp, esrc, ew);

    const int nb = (N_NODES * 64 + 255) / 256;
    gather_pass<<<nb, 256, 0, stream>>>(x, degp, esrc, out);

    const int tiles = (N_NODES + TNODES - 1) / TNODES;   // 782
    node_tiled<<<tiles, 256, 0, stream>>>(out, W0, W1, gamma, beta, ew);
}